// Round 4
// baseline (90.921 us; speedup 1.0000x reference)
//
#include <hip/hip_runtime.h>
#include <hip/hip_bf16.h>
#include <math.h>

// Problem constants: B=1, C=256, H=W=50, N=256 boxes, OUT=7
#define RC    256
#define RH    50
#define RW    50
#define RN    256
#define ROUT  7
#define NBINS 49
#define HW    (RH * RW)

#define XS    50      // max ROI width (x2<=50)
#define YC    2       // rows staged per chunk
#define CSTR  65      // padded channel stride in LDS (odd -> bank-spread writes)

// One block per (box, 64-channel slice). Stage ROI rows into LDS transposed
// ([row][x][c]), pool with lane=channel, coalesced block writeout.
__global__ void __launch_bounds__(256)
roi_pool_fused(const float* __restrict__ feat,
               const float* __restrict__ boxes,
               const int* __restrict__ image_size_p,
               float* __restrict__ out) {
    __shared__ float lds[YC * XS * CSTR];   // 26 KB

    const int n    = blockIdx.x >> 2;
    const int coff = (blockIdx.x & 3) << 6;
    const int t    = threadIdx.x;
    const int w    = t >> 6;          // wave 0..3
    const int lane = t & 63;
    const int sg   = lane >> 4;       // 16-lane sub-segment 0..3
    const int lx   = lane & 15;

    // ---- ROI coords (uniform per block; verified exact vs reference) ----
    float im = (float)(*image_size_p);
    float scale_w = (float)RW / im;
    float scale_h = (float)RH / im;

    float bx = boxes[n * 4 + 0];
    float by = boxes[n * 4 + 1];
    float bw = boxes[n * 4 + 2];
    float bh = boxes[n * 4 + 3];
    bool bad = (bw <= 0.0f) || (bh <= 0.0f);

    float x1f = (bad ? 0.25f * im : bx) * scale_w;
    float x2f = (bad ? 0.75f * im : bx + bw) * scale_w;
    float y1f = (bad ? 0.25f * im : by) * scale_h;
    float y2f = (bad ? 0.75f * im : by + bh) * scale_h;

    int x1 = max(0, (int)x1f);
    int y1 = max(0, (int)y1f);
    int x2 = min(RW, (int)x2f + 1);
    int y2 = min(RH, (int)y2f + 1);
    if (x2 <= x1 + 1) x2 = min(x1 + 2, RW);
    if (y2 <= y1 + 1) y2 = min(y1 + 2, RH);
    x1 = min(max(x1, 0), RW - 2);
    y1 = min(max(y1, 0), RH - 2);
    x2 = max(x1 + 1, min(x2, RW));
    y2 = max(y1 + 1, min(y2, RH));

    const int szx = x2 - x1;
    const int szy = y2 - y1;

    // ---- per-wave bin ranges (bins w, w+4, ..., <49) ----
    int sxA[13], exA[13], syA[13], eyA[13];
    float acc[13];
    #pragma unroll
    for (int k = 0; k < 13; ++k) {
        acc[k] = -INFINITY;
        int b = w + 4 * k;
        if (b < NBINS) {
            int ky = b / ROUT;
            int kx = b - ky * ROUT;
            sxA[k] = x1 + (kx * szx) / ROUT;
            exA[k] = x1 + ((kx + 1) * szx + ROUT - 1) / ROUT;
            syA[k] = y1 + (ky * szy) / ROUT;
            eyA[k] = y1 + ((ky + 1) * szy + ROUT - 1) / ROUT;
        }
    }

    const int nchunk = (szy + YC - 1) / YC;
    for (int ch = 0; ch < nchunk; ++ch) {
        const int cy0 = y1 + ch * YC;

        // ---- stage: 128 segments = 64 ch x 2 rows; coalesced along x ----
        #pragma unroll
        for (int r = 0; r < 8; ++r) {
            int seg = r * 16 + (w << 2) + sg;   // 0..127
            int c   = seg >> 1;
            int yy  = seg & 1;
            int y   = cy0 + yy;
            if (y < y2) {
                const float* __restrict__ src = feat + (coff + c) * HW + y * RW + x1;
                for (int x = lx; x < szx; x += 16)
                    lds[(yy * XS + x) * CSTR + c] = src[x];
            }
        }
        __syncthreads();

        // ---- pool: lane = channel; conflict-free ds_read + fmax ----
        #pragma unroll
        for (int k = 0; k < 13; ++k) {
            int b = w + 4 * k;
            if (b < NBINS) {
                int ys = max(syA[k], cy0);
                int ye = min(eyA[k], cy0 + YC);
                for (int y = ys; y < ye; ++y) {
                    int yy = y - cy0;
                    for (int x = sxA[k]; x < exA[k]; ++x)
                        acc[k] = fmaxf(acc[k], lds[(yy * XS + x - x1) * CSTR + lane]);
                }
            }
        }
        __syncthreads();
    }

    // ---- epilogue: stage results, then coalesced consecutive writeout ----
    #pragma unroll
    for (int k = 0; k < 13; ++k) {
        int b = w + 4 * k;
        if (b < NBINS) lds[b * CSTR + lane] = acc[k];   // max idx 3183 < 6500
    }
    __syncthreads();

    const int obase = (n * RC + coff) * NBINS;
    for (int e = t; e < 64 * NBINS; e += 256) {
        int c = e / NBINS;
        int b = e - c * NBINS;
        out[obase + e] = lds[b * CSTR + c];
    }
}

extern "C" void kernel_launch(void* const* d_in, const int* in_sizes, int n_in,
                              void* d_out, int out_size, void* d_ws, size_t ws_size,
                              hipStream_t stream) {
    const float* feat  = (const float*)d_in[0];
    const float* boxes = (const float*)d_in[1];
    const int* im_sz   = (const int*)d_in[2];
    float* out = (float*)d_out;

    roi_pool_fused<<<RN * 4, 256, 0, stream>>>(feat, boxes, im_sz, out);
}

// Round 5
// 81.208 us; speedup vs baseline: 1.1196x; 1.1196x over previous
//
#include <hip/hip_runtime.h>
#include <hip/hip_bf16.h>
#include <math.h>

// Problem constants: B=1, C=256, H=W=50, N=256 boxes, OUT=7
#define RC    256
#define RH    50
#define RW    50
#define RN    256
#define ROUT  7
#define NBINS 49
#define HW    (RH * RW)

#define CSTR  68     // LDS per-pixel stride (floats): 68%32==4 -> exact 2-way bank aliasing
#define PXMAX 144    // max staged pixels per chunk: bin-height(<=5) * szx(<=26) = 130, +margin

// One block per (box, 64-channel slice). For each bin-row ky (7 chunks):
// stage rows [sy_ky,ey_ky) x 64ch transposed into LDS [px][c], then pool with
// lane=channel and wave-uniform bin loops. Registers hold all 14 bin results.
__global__ void __launch_bounds__(256)
roi_pool_onepass(const float* __restrict__ feat,
                 const float* __restrict__ boxes,
                 const int* __restrict__ image_size_p,
                 float* __restrict__ out) {
    __shared__ float lds[PXMAX * CSTR];   // 39.2 KB

    const int n    = blockIdx.x >> 2;
    const int c0   = (blockIdx.x & 3) << 6;
    const int t    = threadIdx.x;
    const int w    = t >> 6;          // wave 0..3
    const int lane = t & 63;
    const int sg   = lane >> 4;       // 16-lane subgroup within wave
    const int lx   = lane & 15;
    const int g    = (w << 2) | sg;   // global subgroup 0..15

    // ---- ROI coords (exact reference replica; verified rounds 1-4) ----
    float im = (float)(*image_size_p);
    float scale_w = (float)RW / im;
    float scale_h = (float)RH / im;

    float bx = boxes[n * 4 + 0];
    float by = boxes[n * 4 + 1];
    float bw = boxes[n * 4 + 2];
    float bh = boxes[n * 4 + 3];
    bool bad = (bw <= 0.0f) || (bh <= 0.0f);

    float x1f = (bad ? 0.25f * im : bx) * scale_w;
    float x2f = (bad ? 0.75f * im : bx + bw) * scale_w;
    float y1f = (bad ? 0.25f * im : by) * scale_h;
    float y2f = (bad ? 0.75f * im : by + bh) * scale_h;

    int x1 = max(0, (int)x1f);
    int y1 = max(0, (int)y1f);
    int x2 = min(RW, (int)x2f + 1);
    int y2 = min(RH, (int)y2f + 1);
    if (x2 <= x1 + 1) x2 = min(x1 + 2, RW);
    if (y2 <= y1 + 1) y2 = min(y1 + 2, RH);
    x1 = min(max(x1, 0), RW - 2);
    y1 = min(max(y1, 0), RH - 2);
    x2 = max(x1 + 1, min(x2, RW));
    y2 = max(y1 + 1, min(y2, RH));

    const int szx = x2 - x1;
    const int szy = y2 - y1;

    // ---- this wave's two x-bins: kx = w and w+4 ----
    const int kx1v = w + 4;                       // valid only if < 7 (wave 3: invalid)
    const int sx0 = x1 + (w * szx) / ROUT;
    const int ex0 = x1 + ((w + 1) * szx + ROUT - 1) / ROUT;
    const int sx1 = x1 + (kx1v * szx) / ROUT;
    const int ex1 = x1 + ((kx1v + 1) * szx + ROUT - 1) / ROUT;

    float acc[ROUT][2];
    #pragma unroll
    for (int ky = 0; ky < ROUT; ++ky) { acc[ky][0] = -INFINITY; acc[ky][1] = -INFINITY; }

    #pragma unroll
    for (int ky = 0; ky < ROUT; ++ky) {
        const int syk = y1 + (ky * szy) / ROUT;
        const int eyk = y1 + ((ky + 1) * szy + ROUT - 1) / ROUT;
        const int hh  = eyk - syk;                // 1..5

        // ---- stage: hh rows x 64 channels, transposed to [px][c] ----
        // subgroup g handles segments g, g+16, ...; seg -> (row rl, channel c)
        const int nseg = hh << 6;                 // multiple of 16 -> uniform trips
        for (int seg = g; seg < nseg; seg += 16) {
            const int rl = seg >> 6;
            const int c  = seg & 63;
            const float* __restrict__ src = feat + (c0 + c) * HW + (syk + rl) * RW + x1;
            const int pxb = rl * szx;
            for (int x = lx; x < szx; x += 16)    // coalesced 64B per subgroup
                lds[(pxb + x) * CSTR + c] = src[x];
        }
        __syncthreads();

        // ---- pool: wave-uniform loops, lane = channel ----
        float m0 = acc[ky][0];
        float m1 = acc[ky][1];
        for (int rl = 0; rl < hh; ++rl) {
            const float* __restrict__ rowp = lds + rl * szx * CSTR + lane;
            for (int x = sx0; x < ex0; ++x)
                m0 = fmaxf(m0, rowp[(x - x1) * CSTR]);
            if (kx1v < ROUT)
                for (int x = sx1; x < ex1; ++x)
                    m1 = fmaxf(m1, rowp[(x - x1) * CSTR]);
        }
        acc[ky][0] = m0;
        acc[ky][1] = m1;
        __syncthreads();                          // LDS reused by next chunk
    }

    // ---- epilogue: stage 49x64 results, coalesced consecutive writeout ----
    #pragma unroll
    for (int ky = 0; ky < ROUT; ++ky) {
        lds[(ky * ROUT + w) * CSTR + lane] = acc[ky][0];
        if (kx1v < ROUT)
            lds[(ky * ROUT + kx1v) * CSTR + lane] = acc[ky][1];
    }
    __syncthreads();

    const int obase = (n * RC + c0) * NBINS;
    for (int e = t; e < 64 * NBINS; e += 256) {
        const int c = e / NBINS;
        const int b = e - c * NBINS;
        out[obase + e] = lds[b * CSTR + c];
    }
}

extern "C" void kernel_launch(void* const* d_in, const int* in_sizes, int n_in,
                              void* d_out, int out_size, void* d_ws, size_t ws_size,
                              hipStream_t stream) {
    const float* feat  = (const float*)d_in[0];
    const float* boxes = (const float*)d_in[1];
    const int* im_sz   = (const int*)d_in[2];
    float* out = (float*)d_out;

    roi_pool_onepass<<<RN * 4, 256, 0, stream>>>(feat, boxes, im_sz, out);
}

// Round 6
// 31.702 us; speedup vs baseline: 2.8680x; 2.5616x over previous
//
#include <hip/hip_runtime.h>
#include <hip/hip_bf16.h>
#include <math.h>

// Problem constants: B=1, C=256, H=W=50, N=256 boxes, OUT=7
#define RC    256
#define RH    50
#define RW    50
#define RN    256
#define ROUT  7
#define NBINS 49
#define HW    (RH * RW)

// ---------- LDS-tiled transpose: feat[C][HW] -> featT[HW][C] (verified r3) ----------
__global__ void __launch_bounds__(256)
transpose_kernel(const float* __restrict__ feat, float* __restrict__ featT) {
    __shared__ float tile[64][65];
    int ct = blockIdx.x & 3;        // 4 c-tiles (256/64)
    int ht = blockIdx.x >> 2;       // 40 hw-tiles (ceil(2500/64))
    int c0 = ct * 64;
    int h0 = ht * 64;
    int col  = threadIdx.x & 63;
    int row4 = threadIdx.x >> 6;    // 0..3

    #pragma unroll
    for (int i = 0; i < 16; ++i) {
        int r  = row4 + 4 * i;
        int hw = h0 + col;
        if (hw < HW)
            tile[r][col] = feat[(c0 + r) * HW + hw];   // coalesced along hw
    }
    __syncthreads();
    #pragma unroll
    for (int i = 0; i < 16; ++i) {
        int r  = row4 + 4 * i;
        int hw = h0 + r;
        if (hw < HW)
            featT[hw * RC + c0 + col] = tile[col][r];  // coalesced along c
    }
}

// ---------- pool: wave = (box, bin, 64-channel slice); zero divergence ----------
// grid = 256 boxes * 4 cslices * 13 bin-groups; block = 4 waves = 4 consecutive bins.
__global__ void __launch_bounds__(256)
pool_kernel(const float* __restrict__ featT,
            const float* __restrict__ boxes,
            const int* __restrict__ image_size_p,
            float* __restrict__ out) {
    __shared__ float res[64 * 5];   // [c][bin-in-group], stride 5 -> conflict-free

    const int bid = blockIdx.x;
    const int n   = bid / 52;
    const int r0  = bid - n * 52;
    const int cs  = r0 / 13;
    const int bg  = r0 - cs * 13;
    const int t    = threadIdx.x;
    const int w    = t >> 6;
    const int lane = t & 63;

    // ---- ROI coords (exact reference replica; verified rounds 1-5) ----
    float im = (float)(*image_size_p);
    float scale_w = (float)RW / im;
    float scale_h = (float)RH / im;

    float bx = boxes[n * 4 + 0];
    float by = boxes[n * 4 + 1];
    float bw = boxes[n * 4 + 2];
    float bh = boxes[n * 4 + 3];
    bool bad = (bw <= 0.0f) || (bh <= 0.0f);

    float x1f = (bad ? 0.25f * im : bx) * scale_w;
    float x2f = (bad ? 0.75f * im : bx + bw) * scale_w;
    float y1f = (bad ? 0.25f * im : by) * scale_h;
    float y2f = (bad ? 0.75f * im : by + bh) * scale_h;

    int x1 = max(0, (int)x1f);
    int y1 = max(0, (int)y1f);
    int x2 = min(RW, (int)x2f + 1);
    int y2 = min(RH, (int)y2f + 1);
    if (x2 <= x1 + 1) x2 = min(x1 + 2, RW);
    if (y2 <= y1 + 1) y2 = min(y1 + 2, RH);
    x1 = min(max(x1, 0), RW - 2);
    y1 = min(max(y1, 0), RH - 2);
    x2 = max(x1 + 1, min(x2, RW));
    y2 = max(y1 + 1, min(y2, RH));

    const int szx = x2 - x1;
    const int szy = y2 - y1;

    const int bin = bg * 4 + w;
    if (bin < NBINS) {
        const int ky = bin / ROUT;
        const int kx = bin - ky * ROUT;
        const int sx = x1 + (kx * szx) / ROUT;
        const int ex = x1 + ((kx + 1) * szx + ROUT - 1) / ROUT;
        const int sy = y1 + (ky * szy) / ROUT;
        const int ey = y1 + ((ky + 1) * szy + ROUT - 1) / ROUT;

        const float* __restrict__ base = featT + (cs << 6) + lane;
        float m = -INFINITY;
        for (int y = sy; y < ey; ++y) {
            const float* __restrict__ rp = base + (y * RW) * RC;
            int x = sx;
            for (; x + 2 <= ex; x += 2) {          // 2 independent loads in flight
                float v0 = rp[x * RC];
                float v1 = rp[(x + 1) * RC];
                m = fmaxf(m, fmaxf(v0, v1));
            }
            if (x < ex) m = fmaxf(m, rp[x * RC]);
        }
        res[lane * 5 + w] = m;                     // banks spread (5 coprime 32)
    }
    __syncthreads();

    // ---- writeout: thread t -> (c = t>>2, b = t&3); 16B runs per channel ----
    const int b  = t & 3;
    const int c  = t >> 2;
    const int ob = bg * 4 + b;
    if (ob < NBINS)
        out[((n << 8) + (cs << 6) + c) * NBINS + ob] = res[c * 5 + b];
}

extern "C" void kernel_launch(void* const* d_in, const int* in_sizes, int n_in,
                              void* d_out, int out_size, void* d_ws, size_t ws_size,
                              hipStream_t stream) {
    const float* feat  = (const float*)d_in[0];
    const float* boxes = (const float*)d_in[1];
    const int* im_sz   = (const int*)d_in[2];
    float* out   = (float*)d_out;
    float* featT = (float*)d_ws;    // 2.56 MB of ~256 MB scratch

    transpose_kernel<<<160, 256, 0, stream>>>(feat, featT);
    pool_kernel<<<RN * 52, 256, 0, stream>>>(featT, boxes, im_sz, out);
}